// Round 2
// baseline (385.540 us; speedup 1.0000x reference)
//
#include <hip/hip_runtime.h>
#include <math.h>

// Problem constants
#define Bn 2
#define Sn 512
#define Hn 128
#define NHn 4
#define Dn 32
#define BAGn 5
#define NMETAn 16
#define ROWS (Bn * Sn)          // 1024
#define NBn 2

#define NEGF (-4294967295.0f)
#define INV_SQRT_D 0.17677669529663687f
#define SQRT_H 11.313708498984761f
#define EPS_EMB 1e-5f
#define EPSF 1e-8f

template<int N>
static __device__ __forceinline__ float bsum(float v, float* red, int tid) {
    red[tid] = v; __syncthreads();
#pragma unroll
    for (int s = N / 2; s > 0; s >>= 1) {
        if (tid < s) red[tid] += red[tid + s];
        __syncthreads();
    }
    float r = red[0]; __syncthreads();
    return r;
}

template<int N>
static __device__ __forceinline__ float bmaxr(float v, float* red, int tid) {
    red[tid] = v; __syncthreads();
#pragma unroll
    for (int s = N / 2; s > 0; s >>= 1) {
        if (tid < s) red[tid] = fmaxf(red[tid], red[tid + s]);
        __syncthreads();
    }
    float r = red[0]; __syncthreads();
    return r;
}

// ---------------------------------------------------------------------------
// Kernel 1: seq2vec — item/cat/num embed, fusion GEMM, emb LN, keep-mask.
// One block per (b,s) row, 128 threads (one per output channel).
// ---------------------------------------------------------------------------
__global__ __launch_bounds__(128) void embed_kernel(
    const int* __restrict__ ids, const float* __restrict__ meta,
    const int* __restrict__ cats,
    const float* __restrict__ item_w, const float* __restrict__ cat_w,
    const float* __restrict__ numW, const float* __restrict__ numb,
    const float* __restrict__ fusW, const float* __restrict__ fusb,
    const float* __restrict__ lng, const float* __restrict__ lnb,
    float* __restrict__ vecs)
{
    int row = blockIdx.x;        // 0..1023
    int tid = threadIdx.x;       // 0..127
    __shared__ float comb[256];
    __shared__ float red[128];

    int id = ids[row];
    // item part: comb[0..127]
    comb[tid] = item_w[id * Hn + tid] * SQRT_H;
    if (tid < 64) {
        // num_v: comb[128..191]
        float acc = numb[tid];
#pragma unroll
        for (int m = 0; m < NMETAn; ++m)
            acc += meta[row * NMETAn + m] * numW[tid * NMETAn + m];
        comb[128 + tid] = acc;
    } else {
        // cat_v (EmbeddingBag mean, padding_idx=0): comb[192..255]
        int d = tid - 64;
        float acc = 0.f; int cnt = 0;
#pragma unroll
        for (int k = 0; k < BAGn; ++k) {
            int c = cats[row * BAGn + k];
            if (c != 0) { acc += cat_w[c * 64 + d]; cnt++; }
        }
        comb[192 + d] = acc / (float)(cnt > 0 ? cnt : 1);
    }
    __syncthreads();

    // fusion: out[h] = fusion_W[h,:] . comb + b
    float o = fusb[tid];
    const float* wrow = fusW + tid * 256;
    for (int k = 0; k < 256; ++k) o += comb[k] * wrow[k];

    // LayerNorm (eps 1e-5)
    float m = bsum<128>(o, red, tid) * (1.f / 128.f);
    float dlt = o - m;
    float v = bsum<128>(dlt * dlt, red, tid) * (1.f / 128.f);
    float y = dlt / sqrtf(v + EPS_EMB) * lng[tid] + lnb[tid];

    float keep = (id == 0) ? 0.f : 1.f;
    vecs[row * Hn + tid] = y * keep;
}

// ---------------------------------------------------------------------------
// Kernel 2: attn-LN + Q/K/V row-GEMMs. K,V get posK/posV + bias folded in.
// One block per row, 128 threads.
// ---------------------------------------------------------------------------
__global__ __launch_bounds__(128) void qkv_kernel(
    const float* __restrict__ vecs,
    const float* __restrict__ alng, const float* __restrict__ alnb,
    const float* __restrict__ QW, const float* __restrict__ Qb,
    const float* __restrict__ KW, const float* __restrict__ Kb,
    const float* __restrict__ VW, const float* __restrict__ Vb,
    const float* __restrict__ posK, const float* __restrict__ posV,
    float* __restrict__ Qn, float* __restrict__ Q,
    float* __restrict__ K, float* __restrict__ V, int nb)
{
    int row = blockIdx.x, tid = threadIdx.x;
    int s = row & (Sn - 1);
    __shared__ float x[128], qn[128], red[128];

    float xv = vecs[row * Hn + tid];
    x[tid] = xv;
    float m = bsum<128>(xv, red, tid) * (1.f / 128.f);
    float dlt = xv - m;
    float var = bsum<128>(dlt * dlt, red, tid) * (1.f / 128.f);
    float q_n = dlt / sqrtf(var + EPSF) * alng[nb * Hn + tid] + alnb[nb * Hn + tid];
    qn[tid] = q_n;
    Qn[row * Hn + tid] = q_n;
    __syncthreads();

    const float* qw = QW + nb * Hn * Hn + tid * Hn;
    const float* kw = KW + nb * Hn * Hn + tid * Hn;
    const float* vw = VW + nb * Hn * Hn + tid * Hn;
    float aq = Qb[nb * Hn + tid];
    float ak = Kb[nb * Hn + tid];
    float av = Vb[nb * Hn + tid];
    for (int k = 0; k < Hn; ++k) {
        float qk = qn[k], xk = x[k];
        aq += qk * qw[k];
        ak += xk * kw[k];
        av += xk * vw[k];
    }
    Q[row * Hn + tid] = aq;
    K[row * Hn + tid] = ak + posK[s * Hn + tid];
    V[row * Hn + tid] = av + posV[s * Hn + tid];
}

// ---------------------------------------------------------------------------
// Kernel 3: attention. One block per (b, h, query i); 256 threads.
// scores -> softmax -> weighted sum, with time-table gathers fused.
// ---------------------------------------------------------------------------
__global__ __launch_bounds__(256) void attn_kernel(
    const int* __restrict__ ids, const int* __restrict__ tmat,
    const float* __restrict__ Q, const float* __restrict__ K,
    const float* __restrict__ V,
    const float* __restrict__ tKw, const float* __restrict__ tVw,
    float* __restrict__ O)
{
    int bi = blockIdx.x;
    int i = bi & (Sn - 1);
    int h = (bi >> 9) & (NHn - 1);
    int b = bi >> 11;
    int tid = threadIdx.x;

    __shared__ float q[Dn];
    __shared__ float sc[Sn];
    __shared__ float red[256];
    __shared__ float part[256];

    if (tid < Dn) q[tid] = Q[(b * Sn + i) * Hn + h * Dn + tid];
    __syncthreads();

    bool tl = (ids[b * Sn + i] == 0);
    const int* trow = tmat + (b * Sn + i) * Sn;

    // scores
    for (int j = tid; j < Sn; j += 256) {
        float sv;
        if (j > i || tl) {
            sv = NEGF;
        } else {
            int t = trow[j];
            const float* kp = K + (b * Sn + j) * Hn + h * Dn;
            const float* tk = tKw + t * Hn + h * Dn;
            float acc = 0.f;
#pragma unroll
            for (int d = 0; d < Dn; ++d)
                acc += q[d] * (kp[d] + tk[d]);
            sv = acc * INV_SQRT_D;
        }
        sc[j] = sv;
    }
    __syncthreads();

    // softmax
    float lm = fmaxf(sc[tid], sc[tid + 256]);
    float mx = bmaxr<256>(lm, red, tid);
    float e0 = expf(sc[tid] - mx);
    float e1 = expf(sc[tid + 256] - mx);
    sc[tid] = e0; sc[tid + 256] = e1;
    float denom = bsum<256>(e0 + e1, red, tid);
    float inv = 1.f / denom;
    __syncthreads();

    // weighted value sum: 8 j-groups x 32 dims
    int d = tid & (Dn - 1);
    int g = tid >> 5;
    int jmax = tl ? (Sn - 1) : i;
    float acc = 0.f;
    for (int j = g; j <= jmax; j += 8) {
        float p = sc[j];
        int t = trow[j];
        acc += p * (V[(b * Sn + j) * Hn + h * Dn + d] + tVw[t * Hn + h * Dn + d]);
    }
    part[tid] = acc;
    __syncthreads();
    if (tid < Dn) {
        float a = 0.f;
#pragma unroll
        for (int g2 = 0; g2 < 8; ++g2) a += part[g2 * Dn + tid];
        O[(b * Sn + i) * Hn + h * Dn + tid] = a * inv;
    }
}

// ---------------------------------------------------------------------------
// Kernel 4: residual (Qn + attn_out), fwd LN, FFN (gelu), residual, keep.
// One block per row, 128 threads.
// ---------------------------------------------------------------------------
__global__ __launch_bounds__(128) void ffn_kernel(
    const int* __restrict__ ids,
    const float* __restrict__ Qn, const float* __restrict__ O,
    const float* __restrict__ flng, const float* __restrict__ flnb,
    const float* __restrict__ w1W, const float* __restrict__ w1b,
    const float* __restrict__ w2W, const float* __restrict__ w2b,
    float* __restrict__ vecs, int nb)
{
    int row = blockIdx.x, tid = threadIdx.x;
    __shared__ float y[128], h1[128], red[128];

    float xv = Qn[row * Hn + tid] + O[row * Hn + tid];
    float m = bsum<128>(xv, red, tid) * (1.f / 128.f);
    float dlt = xv - m;
    float var = bsum<128>(dlt * dlt, red, tid) * (1.f / 128.f);
    float yv = dlt / sqrtf(var + EPSF) * flng[nb * Hn + tid] + flnb[nb * Hn + tid];
    y[tid] = yv;
    __syncthreads();

    const float* w1 = w1W + nb * Hn * Hn + tid * Hn;
    float a = w1b[nb * Hn + tid];
    for (int k = 0; k < Hn; ++k) a += y[k] * w1[k];
    // exact gelu
    float gl = 0.5f * a * (1.f + erff(a * 0.70710678118654752f));
    h1[tid] = gl;
    __syncthreads();

    const float* w2 = w2W + nb * Hn * Hn + tid * Hn;
    float z = w2b[nb * Hn + tid];
    for (int k = 0; k < Hn; ++k) z += h1[k] * w2[k];
    z += yv;

    float keep = (ids[row] == 0) ? 0.f : 1.f;
    vecs[row * Hn + tid] = z * keep;
}

// ---------------------------------------------------------------------------
// Kernel 5: final LN -> fp32 out
// ---------------------------------------------------------------------------
__global__ __launch_bounds__(128) void final_kernel(
    const float* __restrict__ vecs,
    const float* __restrict__ g, const float* __restrict__ bta,
    float* __restrict__ out)
{
    int row = blockIdx.x, tid = threadIdx.x;
    __shared__ float red[128];
    float xv = vecs[row * Hn + tid];
    float m = bsum<128>(xv, red, tid) * (1.f / 128.f);
    float dlt = xv - m;
    float var = bsum<128>(dlt * dlt, red, tid) * (1.f / 128.f);
    float y = dlt / sqrtf(var + EPSF) * g[tid] + bta[tid];
    out[row * Hn + tid] = y;
}

// ---------------------------------------------------------------------------
extern "C" void kernel_launch(void* const* d_in, const int* in_sizes, int n_in,
                              void* d_out, int out_size, void* d_ws, size_t ws_size,
                              hipStream_t stream) {
    const int*   ids   = (const int*)  d_in[0];
    const float* meta  = (const float*)d_in[1];
    const int*   cats  = (const int*)  d_in[2];
    const int*   tmat  = (const int*)  d_in[3];
    const float* itemw = (const float*)d_in[4];
    const float* catw  = (const float*)d_in[5];
    const float* numW  = (const float*)d_in[6];
    const float* numb  = (const float*)d_in[7];
    const float* fusW  = (const float*)d_in[8];
    const float* fusb  = (const float*)d_in[9];
    const float* elng  = (const float*)d_in[10];
    const float* elnb  = (const float*)d_in[11];
    const float* posK  = (const float*)d_in[12];
    const float* posV  = (const float*)d_in[13];
    const float* tKw   = (const float*)d_in[14];
    const float* tVw   = (const float*)d_in[15];
    const float* alng  = (const float*)d_in[16];
    const float* alnb  = (const float*)d_in[17];
    const float* QW    = (const float*)d_in[18];
    const float* Qb    = (const float*)d_in[19];
    const float* KW    = (const float*)d_in[20];
    const float* Kb    = (const float*)d_in[21];
    const float* VW    = (const float*)d_in[22];
    const float* Vb    = (const float*)d_in[23];
    const float* flng  = (const float*)d_in[24];
    const float* flnb  = (const float*)d_in[25];
    const float* w1W   = (const float*)d_in[26];
    const float* w1b   = (const float*)d_in[27];
    const float* w2W   = (const float*)d_in[28];
    const float* w2b   = (const float*)d_in[29];
    const float* llng  = (const float*)d_in[30];
    const float* llnb  = (const float*)d_in[31];
    (void)in_sizes; (void)n_in; (void)out_size; (void)ws_size;

    float* ws   = (float*)d_ws;
    float* vecs = ws;                 // [1024,128]
    float* Qn   = ws + 131072;        // [1024,128]
    float* Q    = ws + 262144;        // [1024,128]
    float* K    = ws + 393216;        // [1024,128]
    float* V    = ws + 524288;        // [1024,128]
    float* O    = ws + 655360;        // [1024,128]

    float* out = (float*)d_out;

    embed_kernel<<<ROWS, 128, 0, stream>>>(ids, meta, cats, itemw, catw, numW,
                                           numb, fusW, fusb, elng, elnb, vecs);
    for (int nb = 0; nb < NBn; ++nb) {
        qkv_kernel<<<ROWS, 128, 0, stream>>>(vecs, alng, alnb, QW, Qb, KW, Kb,
                                             VW, Vb, posK, posV, Qn, Q, K, V, nb);
        attn_kernel<<<Bn * NHn * Sn, 256, 0, stream>>>(ids, tmat, Q, K, V, tKw,
                                                       tVw, O);
        ffn_kernel<<<ROWS, 128, 0, stream>>>(ids, Qn, O, flng, flnb, w1W, w1b,
                                             w2W, w2b, vecs, nb);
    }
    final_kernel<<<ROWS, 128, 0, stream>>>(vecs, llng, llnb, out);
}